// Round 4
// baseline (492.949 us; speedup 1.0000x reference)
//
#include <hip/hip_runtime.h>
#include <cstdint>
#include <cstddef>

#define HH 300
#define WW 400
#define HWPIX (HH*WW)

typedef __attribute__((ext_vector_type(8))) short short8_t;
typedef __attribute__((ext_vector_type(4))) float f32x4;

static __device__ __forceinline__ unsigned short f2bf(float f){
  union { float f; unsigned u; } v; v.f = f;
  unsigned r = (v.u + 0x7fffu + ((v.u >> 16) & 1u)) >> 16;
  return (unsigned short)r;
}
static __device__ __forceinline__ float bf2f(unsigned short us){
  union { unsigned u; float f; } v; v.u = ((unsigned)us) << 16;
  return v.f;
}
// True per-op-rounded dots: pragma blocks FMA contraction at IR level.
static __device__ __forceinline__ float dot4_x(float a0,float x0,float a1,float x1,
                                               float a2,float x2,float a3,float x3){
  #pragma clang fp contract(off)
  float s = a0*x0;
  s = s + a1*x1;
  s = s + a2*x2;
  s = s + a3*x3;
  return s;
}
static __device__ __forceinline__ float dot3_x(float a0,float x0,float a1,float x1,
                                               float a2,float x2){
  #pragma clang fp contract(off)
  float s = a0*x0;
  s = s + a1*x1;
  s = s + a2*x2;
  return s;
}

// native f32 atomic add (global_atomic_add_f32)
static __device__ __forceinline__ void atomAddF32(float* p, float v){
  unsafeAtomicAdd(p, v);
}

// ---------------------------------------------------------------------------
// prep: zero num/den (grid-stride), transpose W1[0:256] -> W1aT bf16 [n][k]
// (plain row-major, k-contiguous: GEMM waves read their own 64-col slice
// straight from L2), pack ntab, invert poses.
// ---------------------------------------------------------------------------
__global__ void prep_kernel(const float* __restrict__ W1, const float* __restrict__ W2,
                            const float* __restrict__ pose,
                            float* __restrict__ poseinv, unsigned short* __restrict__ W1aT,
                            float* __restrict__ ntab,
                            float* __restrict__ zbuf, int zcount4, int B){
  int tid = threadIdx.x;
  int bid = blockIdx.x;
  // grid-stride zero of num+den (zcount4 float4s)
  {
    float4 z = {0.f,0.f,0.f,0.f};
    int stride = gridDim.x * blockDim.x;
    for (int i = bid*blockDim.x + tid; i < zcount4; i += stride)
      ((float4*)zbuf)[i] = z;
  }
  if (bid < 256){
    int n = bid, k = tid;
    W1aT[n*256 + k] = f2bf(W1[k*256 + n]);
  } else {
    int n = tid;
    ntab[n*8+0] = W1[256*256 + n];
    ntab[n*8+1] = W1[257*256 + n];
    ntab[n*8+2] = W1[258*256 + n];
    ntab[n*8+3] = W2[n*3+0];
    ntab[n*8+4] = W2[n*3+1];
    ntab[n*8+5] = W2[n*3+2];
    ntab[n*8+6] = 0.f; ntab[n*8+7] = 0.f;
    if (tid < B){
      float M[4][8];
      const float* A = pose + tid*16;
      for (int i=0;i<4;i++) for (int j=0;j<4;j++){ M[i][j]=A[i*4+j]; M[i][4+j] = (i==j)?1.f:0.f; }
      for (int c=0;c<4;c++){
        int p=c;
        for (int r=c+1;r<4;r++) if (fabsf(M[r][c])>fabsf(M[p][c])) p=r;
        if (p!=c) for (int j=0;j<8;j++){ float t=M[c][j]; M[c][j]=M[p][j]; M[p][j]=t; }
        float inv = 1.f/M[c][c];
        for (int j=0;j<8;j++) M[c][j]*=inv;
        for (int r=0;r<4;r++) if (r!=c){ float f=M[r][c]; for(int j=0;j<8;j++) M[r][j]-=f*M[c][j]; }
      }
      float* O = poseinv + tid*16;
      for (int i=0;i<4;i++) for (int j=0;j<4;j++) O[i*4+j]=M[i][4+j];
    }
  }
}

// ---------------------------------------------------------------------------
// Fused kernel, barrier-minimized:
//  - preload ALL A (64 verts x 256 k, bf16) into 4 swizzled LDS slabs: 1 barrier
//  - GEMM kt-loop: A-frags from LDS, B-frags DIRECT from global W1aT[n][k]
//    (wave-private col slices, L2-hot) -> NO barriers inside the loop
//  - barrier; epilogue +b1 -> sH (aliases A slabs); barrier
//  - phase 2: projection + vdir MLP tail; part reduce (1 barrier);
//    scatter from ALL 4 waves (wave w: batch w&1, comps {den,r}/{g,b})
// Projection uses contract(off) per-op fp32 in numpy order so pixel binning
// (rintf at .5 boundaries) bit-matches the numpy f32 reference.
// ---------------------------------------------------------------------------
__global__ __launch_bounds__(256) void mlp_scatter_kernel(
    const float* __restrict__ feat, const unsigned short* __restrict__ W1aT,
    const float* __restrict__ b1, const float* __restrict__ b2,
    const float* __restrict__ ntab,
    const float* __restrict__ vp, const float* __restrict__ opy,
    const float* __restrict__ pose, const float* __restrict__ intr,
    const float* __restrict__ poseinv,
    float* __restrict__ num, float* __restrict__ den, int N, int B)
{
  __shared__ __align__(16) char smem[38912];
  unsigned short* sA = (unsigned short*)smem;   // 4 slabs x [64][64] bf16 = 32768 B
  unsigned short* sH = (unsigned short*)smem;   // phase2: 64*256*2 = 32768 B (swizzled rows)
  float* part        = (float*)(smem + 32768);  // phase2: 2*256*3*4 = 6144 B

  const int tid  = threadIdx.x;
  const int lane = tid & 63;
  const int wv   = __builtin_amdgcn_readfirstlane(tid >> 6);
  const int lr   = lane & 15;
  const int qd   = lane >> 4;
  const int m0   = blockIdx.x * 64;

  // ---- preload ALL of A: 16 float4 loads in flight, convert, swizzled store ----
  {
    float4 fr[16];
    #pragma unroll
    for (int s=0;s<4;s++)
      #pragma unroll
      for (int i=0;i<4;i++){
        int q   = i*256 + tid;
        int row = q >> 4;
        int c4  = q & 15;
        long rg = m0 + row; if (rg >= N) rg = N-1;
        fr[s*4+i] = *(const float4*)(feat + rg*256 + s*64 + c4*4);
      }
    #pragma unroll
    for (int s=0;s<4;s++)
      #pragma unroll
      for (int i=0;i<4;i++){
        int q   = i*256 + tid;
        int row = q >> 4;
        int c4  = q & 15;
        float4 f = fr[s*4+i];
        ushort4 u; u.x = f2bf(f.x); u.y = f2bf(f.y); u.z = f2bf(f.z); u.w = f2bf(f.w);
        int q8 = c4 >> 1, half = c4 & 1;
        int phys = q8 ^ (row & 7);
        *(ushort4*)(sA + s*4096 + row*64 + phys*8 + half*4) = u;
      }
  }
  __syncthreads();

  f32x4 acc[4][4];
  #pragma unroll
  for (int i=0;i<4;i++)
    #pragma unroll
    for (int j=0;j<4;j++) acc[i][j] = (f32x4){0.f,0.f,0.f,0.f};

  // ---- GEMM: no barriers; B-frags straight from L2 ----
  const unsigned short* Wb = W1aT + (size_t)(wv*64)*256;  // this wave's col slice
  #pragma unroll
  for (int kt=0; kt<4; kt++){
    #pragma unroll
    for (int ks=0; ks<2; ks++){
      int qlog = ks*4 + qd;
      short8_t av[4], bv[4];
      #pragma unroll
      for (int nt=0; nt<4; nt++)
        bv[nt] = *(const short8_t*)(Wb + (nt*16 + lr)*256 + kt*64 + qlog*8);
      #pragma unroll
      for (int mt=0; mt<4; mt++){
        int row  = mt*16 + lr;
        int phys = qlog ^ (row & 7);
        av[mt] = *(const short8_t*)(sA + kt*4096 + row*64 + phys*8);
      }
      #pragma unroll
      for (int mt=0; mt<4; mt++)
        #pragma unroll
        for (int nt=0; nt<4; nt++)
          acc[mt][nt] = __builtin_amdgcn_mfma_f32_16x16x32_bf16(av[mt], bv[nt], acc[mt][nt], 0,0,0);
    }
  }
  __syncthreads();   // all waves done reading sA; safe to overwrite with sH

  // ---- epilogue: acc + b1 -> sH (rows stride 256, 16B chunks XOR-swizzled) ----
  #pragma unroll
  for (int nt=0; nt<4; nt++){
    int n = wv*64 + nt*16 + lr;
    float bias = b1[n];
    int c = n >> 3, e = n & 7;
    #pragma unroll
    for (int mt=0; mt<4; mt++)
      #pragma unroll
      for (int rr=0; rr<4; rr++){
        int m = mt*16 + qd*4 + rr;   // C/D: row = quad*4+reg, col = lane&15
        sH[m*256 + ((c ^ (m & 7))<<3) + e] = f2bf(acc[mt][nt][rr] + bias);
      }
  }
  __syncthreads();

  // ---- phase 2 ----
  const int r = lane;
  long vg = m0 + r;
  bool rowok = vg < N; if (!rowok) vg = N-1;
  float px = vp[vg], py = vp[(size_t)N+vg], pz = vp[2*(size_t)N+vg];
  const float* tb = ntab + (size_t)wv*64*8;
  const int rsw = r & 7;
  const unsigned short* hrow = sH + r*256;
  float opac = 1.f/(1.f+expf(-opy[vg]));  // clip(sigmoid,0,1) is a no-op

  // hoist this thread's 64 h-values (8 x ds_read_b128)
  short8_t hv[8];
  #pragma unroll
  for (int j8=0;j8<8;j8++){
    int c = wv*8 + j8;
    hv[j8] = *(const short8_t*)(hrow + ((c ^ rsw)<<3));
  }

  for (int b0=0; b0<B; b0+=2){
    int nb = (B - b0 < 2) ? (B - b0) : 2;
    float s_up=-1e6f, s_vp=-1e6f, s_zz=-1e6f;   // this wave's batch = b0 + (wv&1)
    for (int bi=0; bi<nb; bi++){
      int b = b0 + bi;
      const float* P  = pose + b*16;
      const float* Kc = intr + b*9;
      const float* Pi = poseinv + b*16;
      // per-op rounded, in numpy order, contraction OFF
      float xt = dot4_x(P[0],px, P[1],py, P[2], pz, P[3], 1.f);
      float yt = dot4_x(P[4],px, P[5],py, P[6], pz, P[7], 1.f);
      float zt = dot4_x(P[8],px, P[9],py, P[10],pz, P[11],1.f);
      float uu = dot3_x(Kc[0],xt, Kc[1],yt, Kc[2],zt);
      float vv = dot3_x(Kc[3],xt, Kc[4],yt, Kc[5],zt);
      float zp = dot3_x(Kc[6],xt, Kc[7],yt, Kc[8],zt);
      bool em = fabsf(zp) < 0.01f;
      float zsafe = em ? 0.01f : zp;
      float up   = em ? -1e6f : uu/zsafe;   // IEEE correctly-rounded divide
      float vpix = em ? -1e6f : vv/zsafe;
      float zz   = em ? -1e6f : zsafe;
      if (bi == (wv & 1)){ s_up = up; s_vp = vpix; s_zz = zz; }
      float inrm = 1.f/sqrtf(xt*xt + yt*yt + zt*zt);
      float nx=xt*inrm, ny=yt*inrm, nz=zt*inrm;
      float vdx = Pi[0]*nx + Pi[1]*ny + Pi[2]*nz;
      float vdy = Pi[4]*nx + Pi[5]*ny + Pi[6]*nz;
      float vdz = Pi[8]*nx + Pi[9]*ny + Pi[10]*nz;

      float a0=0.f, a1=0.f, a2=0.f;
      #pragma unroll
      for (int j8=0;j8<8;j8++){
        const float* t = tb + j8*64;        // wave-uniform -> s_loads
        #pragma unroll
        for (int e=0;e<8;e++){
          float h = bf2f((unsigned short)hv[j8][e]) + vdx*t[e*8+0] + vdy*t[e*8+1] + vdz*t[e*8+2];
          h = fmaxf(h, 0.f);
          a0 += h*t[e*8+3]; a1 += h*t[e*8+4]; a2 += h*t[e*8+5];
        }
      }
      part[bi*768 + (wv*64 + r)*3 + 0] = a0;
      part[bi*768 + (wv*64 + r)*3 + 1] = a1;
      part[bi*768 + (wv*64 + r)*3 + 2] = a2;
    }
    __syncthreads();
    // all 4 waves scatter: wave w -> batch b0+(w&1); w<2: {den,num0}, w>=2: {num1,num2}
    if ((wv & 1) < nb){
      int b = b0 + (wv & 1);
      const float* pp = part + (wv & 1)*768;
      int ix = (int)rintf(s_up);                 // round-half-even == np.round
      int iy = (int)rintf(s_vp);
      bool valid = rowok && ix>=0 && ix<WW && iy>=0 && iy<HH && s_zz>=1.0f;
      if (valid){
        int idx = iy*WW + ix;
        if (wv < 2){
          float s0 = pp[r*3+0] + pp[(64+r)*3+0] + pp[(128+r)*3+0] + pp[(192+r)*3+0];
          float r0 = 1.f/(1.f+expf(-(s0 + b2[0])));
          atomAddF32(den + (size_t)b*HWPIX + idx, opac);
          atomAddF32(num + ((size_t)b*3+0)*HWPIX + idx, opac*r0);
        } else {
          float s1 = pp[r*3+1] + pp[(64+r)*3+1] + pp[(128+r)*3+1] + pp[(192+r)*3+1];
          float s2 = pp[r*3+2] + pp[(64+r)*3+2] + pp[(128+r)*3+2] + pp[(192+r)*3+2];
          float r1 = 1.f/(1.f+expf(-(s1 + b2[1])));
          float r2 = 1.f/(1.f+expf(-(s2 + b2[2])));
          atomAddF32(num + ((size_t)b*3+1)*HWPIX + idx, opac*r1);
          atomAddF32(num + ((size_t)b*3+2)*HWPIX + idx, opac*r2);
        }
      }
    }
    if (b0 + 2 < B) __syncthreads();
  }
}

// ---------------------------------------------------------------------------
// In-place: d_out currently holds num (B,3,HW); convert to final image.
__global__ void compose_kernel(float* __restrict__ out, const float* __restrict__ den,
                               const float* __restrict__ bkg, int B){
  int i = blockIdx.x*256 + threadIdx.x;
  int total = B*HWPIX;
  if (i >= total) return;
  int b = i / HWPIX;
  int pix = i - b*HWPIX;
  float d = den[i];
  float alpha = 1.f - expf(-d);
  float om = 1.f - alpha;
  float dd = d + 1e-8f;
  float* ob = out + (size_t)b*3*HWPIX;
  float f0 = ob[0*HWPIX + pix] / dd;
  float f1 = ob[1*HWPIX + pix] / dd;
  float f2 = ob[2*HWPIX + pix] / dd;
  ob[0*HWPIX + pix] = f0*alpha + bkg[0]*om;
  ob[1*HWPIX + pix] = f1*alpha + bkg[1]*om;
  ob[2*HWPIX + pix] = f2*alpha + bkg[2]*om;
}

// ---------------------------------------------------------------------------
extern "C" void kernel_launch(void* const* d_in, const int* in_sizes, int n_in,
                              void* d_out, int out_size, void* d_ws, size_t ws_size,
                              hipStream_t stream){
  const float* vp   = (const float*)d_in[0];
  // d_in[1] = ref_images: unused by the reference computation
  const float* pose = (const float*)d_in[2];
  const float* intr = (const float*)d_in[3];
  const float* feat = (const float*)d_in[4];
  const float* opy  = (const float*)d_in[5];
  const float* W1   = (const float*)d_in[6];
  const float* b1   = (const float*)d_in[7];
  const float* W2   = (const float*)d_in[8];
  const float* b2   = (const float*)d_in[9];
  const float* bkg  = (const float*)d_in[10];
  float* out = (float*)d_out;
  int N = in_sizes[0]/3;
  int B = in_sizes[2]/16;

  char* ws = (char*)d_ws;
  float* poseinv        = (float*)ws;                          // 256 B
  unsigned short* W1aT  = (unsigned short*)(ws + 256);         // 131072 B ([n][k] bf16)
  float* ntab           = (float*)(ws + 256 + 131072);         // 8192 B
  float* den            = (float*)(ws + 256 + 131072 + 8192);  // B*HWPIX floats

  // prep zeroes out (=num) and den; out and den are adjacent targets:
  // zero them as two regions via one grid-stride over out then den?  out is
  // d_out (separate allocation) — zero both: pass out ptr and count for out,
  // den handled by the same kernel via second region trick: we zero out and
  // den separately by launching prep with zbuf=out covering out, then den is
  // zeroed by the same grid-stride (den contiguous in ws, separate pointer).
  // Simplest: two regions -> zero `out` (B*3*HWPIX) and `den` (B*HWPIX).
  // We fold den into the same call by zeroing max region: use two calls? No:
  // prep zeroes out only; den zero folded via zbuf2 loop below (den is in ws
  // right after ntab, so zero ntab-aligned? keep it simple: zero den too in
  // prep by extending the grid-stride over a second pointer).
  prep_kernel<<<257, 256, 0, stream>>>(W1, W2, pose, poseinv, W1aT, ntab,
                                       out, (B*3*HWPIX)/4, B);
  hipMemsetAsync(den, 0, (size_t)B*HWPIX*sizeof(float), stream);
  int gridM = (N + 63)/64;
  mlp_scatter_kernel<<<gridM, 256, 0, stream>>>(feat, W1aT, b1, b2, ntab, vp, opy,
                                                pose, intr, poseinv, out, den, N, B);
  compose_kernel<<<(B*HWPIX + 255)/256, 256, 0, stream>>>(out, den, bkg, B);
}

// Round 6
// 414.207 us; speedup vs baseline: 1.1901x; 1.1901x over previous
//
#include <hip/hip_runtime.h>
#include <cstdint>
#include <cstddef>

#define HH 300
#define WW 400
#define HWPIX (HH*WW)

typedef __attribute__((ext_vector_type(8))) short short8_t;
typedef __attribute__((ext_vector_type(4))) float f32x4;

static __device__ __forceinline__ unsigned short f2bf(float f){
  union { float f; unsigned u; } v; v.f = f;
  unsigned r = (v.u + 0x7fffu + ((v.u >> 16) & 1u)) >> 16;
  return (unsigned short)r;
}
static __device__ __forceinline__ float bf2f(unsigned short us){
  union { unsigned u; float f; } v; v.u = ((unsigned)us) << 16;
  return v.f;
}
// True per-op-rounded dots: pragma blocks FMA contraction at IR level.
static __device__ __forceinline__ float dot4_x(float a0,float x0,float a1,float x1,
                                               float a2,float x2,float a3,float x3){
  #pragma clang fp contract(off)
  float s = a0*x0;
  s = s + a1*x1;
  s = s + a2*x2;
  s = s + a3*x3;
  return s;
}
static __device__ __forceinline__ float dot3_x(float a0,float x0,float a1,float x1,
                                               float a2,float x2){
  #pragma clang fp contract(off)
  float s = a0*x0;
  s = s + a1*x1;
  s = s + a2*x2;
  return s;
}

// async global->LDS, 16B per lane (size must be a literal)
static __device__ __forceinline__ void gload_lds16(const void* g, void* l){
  __builtin_amdgcn_global_load_lds(
      (const __attribute__((address_space(1))) unsigned int*)g,
      (__attribute__((address_space(3))) unsigned int*)l, 16, 0, 0);
}

// native f32 atomic add (global_atomic_add_f32)
static __device__ __forceinline__ void atomAddF32(float* p, float v){
  unsafeAtomicAdd(p, v);
}

// ---------------------------------------------------------------------------
// prep: blocks 0..255 (block = k-row, coalesced W1 reads) write W1[0:256]
// transposed+bf16 in the swizzled LDS-image layout (4 kt-images of 32 KB;
// within an image: n*64 + ((c8 ^ (n&7))*8) + i for k = kt*64 + c8*8 + i).
// block 256 packs ntab[n][8] = {W1 rows 256..258 (vdir), W2 cols 0..2, pad}
// and inverts poses.
// ---------------------------------------------------------------------------
__global__ void prep_kernel(const float* __restrict__ W1, const float* __restrict__ W2,
                            const float* __restrict__ pose,
                            float* __restrict__ poseinv, unsigned short* __restrict__ W1aT,
                            float* __restrict__ ntab, int B){
  int tid = threadIdx.x;
  int bid = blockIdx.x;
  if (bid < 256){
    int k = bid, n = tid;
    int kt = k >> 6;
    int c8 = (k >> 3) & 7;
    int i  = k & 7;
    W1aT[kt*16384 + n*64 + ((c8 ^ (n & 7))<<3) + i] = f2bf(W1[k*256 + n]);
  } else {
    int n = tid;
    ntab[n*8+0] = W1[256*256 + n];
    ntab[n*8+1] = W1[257*256 + n];
    ntab[n*8+2] = W1[258*256 + n];
    ntab[n*8+3] = W2[n*3+0];
    ntab[n*8+4] = W2[n*3+1];
    ntab[n*8+5] = W2[n*3+2];
    ntab[n*8+6] = 0.f; ntab[n*8+7] = 0.f;
    if (tid < B){
      float M[4][8];
      const float* A = pose + tid*16;
      for (int i=0;i<4;i++) for (int j=0;j<4;j++){ M[i][j]=A[i*4+j]; M[i][4+j] = (i==j)?1.f:0.f; }
      for (int c=0;c<4;c++){
        int p=c;
        for (int r=c+1;r<4;r++) if (fabsf(M[r][c])>fabsf(M[p][c])) p=r;
        if (p!=c) for (int j=0;j<8;j++){ float t=M[c][j]; M[c][j]=M[p][j]; M[p][j]=t; }
        float inv = 1.f/M[c][c];
        for (int j=0;j<8;j++) M[c][j]*=inv;
        for (int r=0;r<4;r++) if (r!=c){ float f=M[r][c]; for(int j=0;j<8;j++) M[r][j]-=f*M[c][j]; }
      }
      float* O = poseinv + tid*16;
      for (int i=0;i<4;i++) for (int j=0;j<4;j++) O[i*4+j]=M[i][4+j];
    }
  }
}

// ---------------------------------------------------------------------------
// Fused: bf16 MFMA GEMM (r3 structure: global_load_lds B, A reg-prefetch)
// -> +b1 -> LDS(bf16, chunk-swizzled rows) -> BATCH-MERGED phase 2 (each t
// row loaded once, used for both batches; h unpacked once) -> part reduce
// -> native-atomic scatter (all 4 waves: wave w -> batch w&1, comps split).
// Projection uses contract(off) per-op fp32 in numpy order so pixel binning
// (rintf at .5 boundaries) bit-matches the numpy f32 reference.
// ---------------------------------------------------------------------------
__global__ __launch_bounds__(256) void mlp_scatter_kernel(
    const float* __restrict__ feat, const unsigned short* __restrict__ W1aT,
    const float* __restrict__ b1, const float* __restrict__ b2,
    const float* __restrict__ ntab,
    const float* __restrict__ vp, const float* __restrict__ opy,
    const float* __restrict__ pose, const float* __restrict__ intr,
    const float* __restrict__ poseinv,
    float* __restrict__ num, float* __restrict__ den, int N, int B)
{
  __shared__ __align__(16) char smem[40960];
  unsigned short* sA = (unsigned short*)smem;            // phase1: 64*64*2  = 8192 B
  unsigned short* sB = (unsigned short*)(smem + 8192);   // phase1: 256*64*2 = 32768 B
  unsigned short* sH = (unsigned short*)smem;            // phase2: 64*256*2 = 32768 B (swizzled rows)
  float* part        = (float*)(smem + 32768);           // phase2: 2*256*3*4 = 6144 B

  const int tid  = threadIdx.x;
  const int lane = tid & 63;
  const int wv   = __builtin_amdgcn_readfirstlane(tid >> 6);
  const int lr   = lane & 15;
  const int qd   = lane >> 4;
  const int m0   = blockIdx.x * 64;

  f32x4 acc[4][4];
  for (int i=0;i<4;i++) for (int j=0;j<4;j++) acc[i][j] = (f32x4){0.f,0.f,0.f,0.f};

  // A prefetch registers (already converted to bf16: 8 VGPRs)
  ushort4 uA[4];
  {
    #pragma unroll
    for (int i=0;i<4;i++){
      int q   = i*256 + tid;
      int row = q >> 4;
      int c4  = q & 15;
      long rg = m0 + row; if (rg >= N) rg = N-1;
      float4 f = *(const float4*)(feat + rg*256 + c4*4);
      ushort4 u; u.x = f2bf(f.x); u.y = f2bf(f.y); u.z = f2bf(f.z); u.w = f2bf(f.w);
      uA[i] = u;
    }
  }

  for (int kt=0; kt<4; kt++){
    // ---- stage A from prefetched regs (swizzled ds_write) ----
    #pragma unroll
    for (int i=0;i<4;i++){
      int q   = i*256 + tid;
      int row = q >> 4;
      int c4  = q & 15;
      int q8 = c4 >> 1, half = c4 & 1;
      int phys = q8 ^ (row & 7);
      *(ushort4*)(sA + row*64 + phys*8 + half*4) = uA[i];
    }
    // ---- stage B: pure linear async copy of the pre-swizzled 32 KB image ----
    {
      const unsigned int* gim = (const unsigned int*)(W1aT + kt*16384);
      unsigned int* lim = (unsigned int*)sB;
      #pragma unroll
      for (int i=0;i<8;i++)
        gload_lds16(gim + i*1024 + tid*4, lim + i*1024 + tid*4);
    }
    __syncthreads();   // drains vmcnt: B tile resident

    // ---- prefetch next A during the MFMA phase ----
    if (kt < 3){
      #pragma unroll
      for (int i=0;i<4;i++){
        int q   = i*256 + tid;
        int row = q >> 4;
        int c4  = q & 15;
        long rg = m0 + row; if (rg >= N) rg = N-1;
        float4 f = *(const float4*)(feat + rg*256 + (kt+1)*64 + c4*4);
        ushort4 u; u.x = f2bf(f.x); u.y = f2bf(f.y); u.z = f2bf(f.z); u.w = f2bf(f.w);
        uA[i] = u;
      }
    }

    #pragma unroll
    for (int ks=0; ks<2; ks++){
      short8_t av[4], bv[4];
      int qlog = ks*4 + qd;
      #pragma unroll
      for (int mt=0; mt<4; mt++){
        int row  = mt*16 + lr;
        int phys = qlog ^ (row & 7);
        av[mt] = *(const short8_t*)(sA + row*64 + phys*8);
      }
      #pragma unroll
      for (int nt=0; nt<4; nt++){
        int n    = wv*64 + nt*16 + lr;
        int phys = qlog ^ (n & 7);
        bv[nt] = *(const short8_t*)(sB + n*64 + phys*8);
      }
      #pragma unroll
      for (int mt=0; mt<4; mt++)
        #pragma unroll
        for (int nt=0; nt<4; nt++)
          acc[mt][nt] = __builtin_amdgcn_mfma_f32_16x16x32_bf16(av[mt], bv[nt], acc[mt][nt], 0,0,0);
    }
    __syncthreads();
  }

  // ---- epilogue: acc + b1 -> sH (rows stride 256, 16B chunks XOR-swizzled) ----
  #pragma unroll
  for (int nt=0; nt<4; nt++){
    int n = wv*64 + nt*16 + lr;
    float bias = b1[n];
    int c = n >> 3, e = n & 7;
    #pragma unroll
    for (int mt=0; mt<4; mt++)
      #pragma unroll
      for (int rr=0; rr<4; rr++){
        int m = mt*16 + qd*4 + rr;   // C/D: row = quad*4+reg, col = lane&15
        sH[m*256 + ((c ^ (m & 7))<<3) + e] = f2bf(acc[mt][nt][rr] + bias);
      }
  }
  __syncthreads();

  // ---- phase 2 (batch-merged) ----
  const int r = lane;
  long vg = m0 + r;
  bool rowok = vg < N; if (!rowok) vg = N-1;
  float px = vp[vg], py = vp[(size_t)N+vg], pz = vp[2*(size_t)N+vg];
  const float* tb = ntab + (size_t)wv*64*8;
  const int rsw = r & 7;
  const unsigned short* hrow = sH + r*256;
  float opac = 1.f/(1.f+expf(-opy[vg]));  // clip(sigmoid,0,1) is a no-op

  // hoist this thread's 64 h-values (8 x ds_read_b128)
  short8_t hv[8];
  #pragma unroll
  for (int j8=0;j8<8;j8++){
    int c = wv*8 + j8;
    hv[j8] = *(const short8_t*)(hrow + ((c ^ rsw)<<3));
  }

  for (int b0=0; b0<B; b0+=2){
    int nb = (B - b0 < 2) ? (B - b0) : 2;
    float vdx0=0.f, vdy0=0.f, vdz0=0.f, sup0=-1e6f, svp0=-1e6f, szz0=-1e6f;
    float vdx1=0.f, vdy1=0.f, vdz1=0.f, sup1=-1e6f, svp1=-1e6f, szz1=-1e6f;
    #pragma unroll
    for (int bi=0; bi<2; bi++){
      if (bi < nb){
        int b = b0 + bi;
        const float* P  = pose + b*16;
        const float* Kc = intr + b*9;
        const float* Pi = poseinv + b*16;
        // per-op rounded, in numpy order, contraction OFF
        float xt = dot4_x(P[0],px, P[1],py, P[2], pz, P[3], 1.f);
        float yt = dot4_x(P[4],px, P[5],py, P[6], pz, P[7], 1.f);
        float zt = dot4_x(P[8],px, P[9],py, P[10],pz, P[11],1.f);
        float uu = dot3_x(Kc[0],xt, Kc[1],yt, Kc[2],zt);
        float vv = dot3_x(Kc[3],xt, Kc[4],yt, Kc[5],zt);
        float zp = dot3_x(Kc[6],xt, Kc[7],yt, Kc[8],zt);
        bool em = fabsf(zp) < 0.01f;
        float zsafe = em ? 0.01f : zp;
        float up   = em ? -1e6f : uu/zsafe;   // IEEE correctly-rounded divide
        float vpix = em ? -1e6f : vv/zsafe;
        float zz   = em ? -1e6f : zsafe;
        float inrm = 1.f/sqrtf(xt*xt + yt*yt + zt*zt);
        float nx=xt*inrm, ny=yt*inrm, nz=zt*inrm;
        float vx = Pi[0]*nx + Pi[1]*ny + Pi[2]*nz;
        float vy = Pi[4]*nx + Pi[5]*ny + Pi[6]*nz;
        float vz = Pi[8]*nx + Pi[9]*ny + Pi[10]*nz;
        if (bi == 0){ vdx0=vx; vdy0=vy; vdz0=vz; sup0=up; svp0=vpix; szz0=zz; }
        else        { vdx1=vx; vdy1=vy; vdz1=vz; sup1=up; svp1=vpix; szz1=zz; }
      }
    }
    // merged j-loop: t loaded once, h unpacked once, both batches accumulated
    float a00=0.f,a01=0.f,a02=0.f, a10=0.f,a11=0.f,a12=0.f;
    #pragma unroll
    for (int j8=0;j8<8;j8++){
      #pragma unroll
      for (int e=0;e<8;e++){
        const float* t = tb + (j8*8+e)*8;   // wave-uniform address -> s_loads
        float t0=t[0], t1=t[1], t2=t[2], t3=t[3], t4=t[4], t5=t[5];
        float hb = bf2f((unsigned short)hv[j8][e]);
        float h0 = fmaxf(hb + vdx0*t0 + vdy0*t1 + vdz0*t2, 0.f);
        float h1 = fmaxf(hb + vdx1*t0 + vdy1*t1 + vdz1*t2, 0.f);
        a00 += h0*t3; a01 += h0*t4; a02 += h0*t5;
        a10 += h1*t3; a11 += h1*t4; a12 += h1*t5;
      }
    }
    {
      int base = (wv*64 + r)*3;
      part[base+0] = a00; part[base+1] = a01; part[base+2] = a02;
      part[768+base+0] = a10; part[768+base+1] = a11; part[768+base+2] = a12;
    }
    __syncthreads();
    // all 4 waves scatter: wave w -> batch b0+(w&1); w<2: {den,num0}, w>=2: {num1,num2}
    if ((wv & 1) < nb){
      int b = b0 + (wv & 1);
      const float* pp = part + (wv & 1)*768;
      float S_up = (wv & 1) ? sup1 : sup0;
      float S_vp = (wv & 1) ? svp1 : svp0;
      float S_zz = (wv & 1) ? szz1 : szz0;
      int ix = (int)rintf(S_up);                 // round-half-even == np.round
      int iy = (int)rintf(S_vp);
      bool valid = rowok && ix>=0 && ix<WW && iy>=0 && iy<HH && S_zz>=1.0f;
      if (valid){
        int idx = iy*WW + ix;
        if (wv < 2){
          float s0 = pp[r*3+0] + pp[(64+r)*3+0] + pp[(128+r)*3+0] + pp[(192+r)*3+0];
          float r0 = 1.f/(1.f+expf(-(s0 + b2[0])));
          atomAddF32(den + (size_t)b*HWPIX + idx, opac);
          atomAddF32(num + ((size_t)b*3+0)*HWPIX + idx, opac*r0);
        } else {
          float s1 = pp[r*3+1] + pp[(64+r)*3+1] + pp[(128+r)*3+1] + pp[(192+r)*3+1];
          float s2 = pp[r*3+2] + pp[(64+r)*3+2] + pp[(128+r)*3+2] + pp[(192+r)*3+2];
          float r1 = 1.f/(1.f+expf(-(s1 + b2[1])));
          float r2 = 1.f/(1.f+expf(-(s2 + b2[2])));
          atomAddF32(num + ((size_t)b*3+1)*HWPIX + idx, opac*r1);
          atomAddF32(num + ((size_t)b*3+2)*HWPIX + idx, opac*r2);
        }
      }
    }
    if (b0 + 2 < B) __syncthreads();
  }
}

// ---------------------------------------------------------------------------
// num/den (workspace) -> final planar image; writes every out pixel, so no
// out memset is needed.
__global__ void compose_kernel(float* __restrict__ out, const float* __restrict__ num,
                               const float* __restrict__ den,
                               const float* __restrict__ bkg, int B){
  int i = blockIdx.x*256 + threadIdx.x;
  int total = B*HWPIX;
  if (i >= total) return;
  int b = i / HWPIX;
  int pix = i - b*HWPIX;
  float d = den[i];
  float alpha = 1.f - expf(-d);
  float om = 1.f - alpha;
  float dd = d + 1e-8f;
  const float* nb_ = num + (size_t)b*3*HWPIX;
  float* ob = out + (size_t)b*3*HWPIX;
  ob[0*HWPIX + pix] = (nb_[0*HWPIX + pix]/dd)*alpha + bkg[0]*om;
  ob[1*HWPIX + pix] = (nb_[1*HWPIX + pix]/dd)*alpha + bkg[1]*om;
  ob[2*HWPIX + pix] = (nb_[2*HWPIX + pix]/dd)*alpha + bkg[2]*om;
}

// ---------------------------------------------------------------------------
extern "C" void kernel_launch(void* const* d_in, const int* in_sizes, int n_in,
                              void* d_out, int out_size, void* d_ws, size_t ws_size,
                              hipStream_t stream){
  const float* vp   = (const float*)d_in[0];
  // d_in[1] = ref_images: unused by the reference computation
  const float* pose = (const float*)d_in[2];
  const float* intr = (const float*)d_in[3];
  const float* feat = (const float*)d_in[4];
  const float* opy  = (const float*)d_in[5];
  const float* W1   = (const float*)d_in[6];
  const float* b1   = (const float*)d_in[7];
  const float* W2   = (const float*)d_in[8];
  const float* b2   = (const float*)d_in[9];
  const float* bkg  = (const float*)d_in[10];
  float* out = (float*)d_out;
  int N = in_sizes[0]/3;
  int B = in_sizes[2]/16;

  char* ws = (char*)d_ws;
  float* poseinv        = (float*)ws;                          // 256 B
  unsigned short* W1aT  = (unsigned short*)(ws + 256);         // 131072 B (4 pre-swizzled kt-images)
  float* ntab           = (float*)(ws + 256 + 131072);         // 8192 B
  float* num            = (float*)(ws + 256 + 131072 + 8192);  // B*3*HWPIX floats
  float* den            = num + (size_t)B*3*HWPIX;             // B*HWPIX floats

  // one memset covers num + den (contiguous); out needs none (compose writes all)
  hipMemsetAsync(num, 0, (size_t)B*4*HWPIX*sizeof(float), stream);
  prep_kernel<<<257, 256, 0, stream>>>(W1, W2, pose, poseinv, W1aT, ntab, B);
  int gridM = (N + 63)/64;
  mlp_scatter_kernel<<<gridM, 256, 0, stream>>>(feat, W1aT, b1, b2, ntab, vp, opy,
                                                pose, intr, poseinv, num, den, N, B);
  compose_kernel<<<(B*HWPIX + 255)/256, 256, 0, stream>>>(out, num, den, bkg, B);
}

// Round 7
// 408.262 us; speedup vs baseline: 1.2074x; 1.0146x over previous
//
#include <hip/hip_runtime.h>
#include <cstdint>
#include <cstddef>

#define HH 300
#define WW 400
#define HWPIX (HH*WW)

typedef __attribute__((ext_vector_type(8))) short short8_t;
typedef __attribute__((ext_vector_type(4))) float f32x4;

static __device__ __forceinline__ unsigned short f2bf(float f){
  union { float f; unsigned u; } v; v.f = f;
  unsigned r = (v.u + 0x7fffu + ((v.u >> 16) & 1u)) >> 16;
  return (unsigned short)r;
}
static __device__ __forceinline__ float bf2f(unsigned short us){
  union { unsigned u; float f; } v; v.u = ((unsigned)us) << 16;
  return v.f;
}
// True per-op-rounded dots: pragma blocks FMA contraction at IR level.
static __device__ __forceinline__ float dot4_x(float a0,float x0,float a1,float x1,
                                               float a2,float x2,float a3,float x3){
  #pragma clang fp contract(off)
  float s = a0*x0;
  s = s + a1*x1;
  s = s + a2*x2;
  s = s + a3*x3;
  return s;
}
static __device__ __forceinline__ float dot3_x(float a0,float x0,float a1,float x1,
                                               float a2,float x2){
  #pragma clang fp contract(off)
  float s = a0*x0;
  s = s + a1*x1;
  s = s + a2*x2;
  return s;
}

// async global->LDS, 16B per lane (size must be a literal)
static __device__ __forceinline__ void gload_lds16(const void* g, void* l){
  __builtin_amdgcn_global_load_lds(
      (const __attribute__((address_space(1))) unsigned int*)g,
      (__attribute__((address_space(3))) unsigned int*)l, 16, 0, 0);
}

// native f32 atomic add (global_atomic_add_f32)
static __device__ __forceinline__ void atomAddF32(float* p, float v){
  unsafeAtomicAdd(p, v);
}

// ---------------------------------------------------------------------------
// prep: grid-stride zero of num+den (replaces the hipMemsetAsync dispatch),
// then blocks 0..255 (block = k-row) write W1[0:256] transposed+bf16 in the
// swizzled LDS-image layout (4 kt-images of 32 KB; within an image:
// n*64 + ((c8 ^ (n&7))*8) + i for k = kt*64 + c8*8 + i).
// block 256 packs ntab[n][8] = {W1 rows 256..258 (vdir), W2 cols 0..2, pad}
// and inverts poses.
// ---------------------------------------------------------------------------
__global__ void prep_kernel(const float* __restrict__ W1, const float* __restrict__ W2,
                            const float* __restrict__ pose,
                            float* __restrict__ poseinv, unsigned short* __restrict__ W1aT,
                            float* __restrict__ ntab,
                            float* __restrict__ zbuf, int zcount4, int B){
  int tid = threadIdx.x;
  int bid = blockIdx.x;
  // zero num+den (zcount4 float4s), all blocks participate
  {
    float4 z = {0.f,0.f,0.f,0.f};
    int stride = gridDim.x * blockDim.x;
    for (int i = bid*blockDim.x + tid; i < zcount4; i += stride)
      ((float4*)zbuf)[i] = z;
  }
  if (bid < 256){
    int k = bid, n = tid;
    int kt = k >> 6;
    int c8 = (k >> 3) & 7;
    int i  = k & 7;
    W1aT[kt*16384 + n*64 + ((c8 ^ (n & 7))<<3) + i] = f2bf(W1[k*256 + n]);
  } else {
    int n = tid;
    ntab[n*8+0] = W1[256*256 + n];
    ntab[n*8+1] = W1[257*256 + n];
    ntab[n*8+2] = W1[258*256 + n];
    ntab[n*8+3] = W2[n*3+0];
    ntab[n*8+4] = W2[n*3+1];
    ntab[n*8+5] = W2[n*3+2];
    ntab[n*8+6] = 0.f; ntab[n*8+7] = 0.f;
    if (tid < B){
      float M[4][8];
      const float* A = pose + tid*16;
      for (int i=0;i<4;i++) for (int j=0;j<4;j++){ M[i][j]=A[i*4+j]; M[i][4+j] = (i==j)?1.f:0.f; }
      for (int c=0;c<4;c++){
        int p=c;
        for (int r=c+1;r<4;r++) if (fabsf(M[r][c])>fabsf(M[p][c])) p=r;
        if (p!=c) for (int j=0;j<8;j++){ float t=M[c][j]; M[c][j]=M[p][j]; M[p][j]=t; }
        float inv = 1.f/M[c][c];
        for (int j=0;j<8;j++) M[c][j]*=inv;
        for (int r=0;r<4;r++) if (r!=c){ float f=M[r][c]; for(int j=0;j<8;j++) M[r][j]-=f*M[c][j]; }
      }
      float* O = poseinv + tid*16;
      for (int i=0;i<4;i++) for (int j=0;j<4;j++) O[i*4+j]=M[i][4+j];
    }
  }
}

// ---------------------------------------------------------------------------
// Fused: bf16 MFMA GEMM (global_load_lds B, A reg-prefetch) -> +b1 ->
// LDS(bf16, chunk-swizzled rows) -> BATCH-MERGED phase 2 with ntab staged
// in LDS (t-rows via pipelined ds_read_b128/b64 instead of latency-bound
// scalar loads) -> part reduce -> native-atomic scatter (all 4 waves).
// LDS map: [0,8K) sA | [8K,40K) sB | phase2: [0,32K) sH, [32K,38K) part |
// [40K,48K) ntab copy (never aliased, staged once at kernel start).
// Projection uses contract(off) per-op fp32 in numpy order so pixel binning
// (rintf at .5 boundaries) bit-matches the numpy f32 reference.
// ---------------------------------------------------------------------------
__global__ __launch_bounds__(256) void mlp_scatter_kernel(
    const float* __restrict__ feat, const unsigned short* __restrict__ W1aT,
    const float* __restrict__ b1, const float* __restrict__ b2,
    const float* __restrict__ ntab,
    const float* __restrict__ vp, const float* __restrict__ opy,
    const float* __restrict__ pose, const float* __restrict__ intr,
    const float* __restrict__ poseinv,
    float* __restrict__ num, float* __restrict__ den, int N, int B)
{
  __shared__ __align__(16) char smem[49152];
  unsigned short* sA = (unsigned short*)smem;            // phase1: 64*64*2  = 8192 B
  unsigned short* sB = (unsigned short*)(smem + 8192);   // phase1: 256*64*2 = 32768 B
  unsigned short* sH = (unsigned short*)smem;            // phase2: 64*256*2 = 32768 B (swizzled rows)
  float* part        = (float*)(smem + 32768);           // phase2: 2*256*3*4 = 6144 B
  float* tlds        = (float*)(smem + 40960);           // ntab copy: 8192 B (persistent)

  const int tid  = threadIdx.x;
  const int lane = tid & 63;
  const int wv   = __builtin_amdgcn_readfirstlane(tid >> 6);
  const int lr   = lane & 15;
  const int qd   = lane >> 4;
  const int m0   = blockIdx.x * 64;

  // ---- stage ntab into LDS (2 x 16B per thread); drained by the kt=0 barrier ----
  {
    const unsigned int* g = (const unsigned int*)ntab;
    unsigned int* l = (unsigned int*)tlds;
    gload_lds16(g + tid*4, l + tid*4);
    gload_lds16(g + 1024 + tid*4, l + 1024 + tid*4);
  }

  f32x4 acc[4][4];
  for (int i=0;i<4;i++) for (int j=0;j<4;j++) acc[i][j] = (f32x4){0.f,0.f,0.f,0.f};

  // A prefetch registers (already converted to bf16: 8 VGPRs)
  ushort4 uA[4];
  {
    #pragma unroll
    for (int i=0;i<4;i++){
      int q   = i*256 + tid;
      int row = q >> 4;
      int c4  = q & 15;
      long rg = m0 + row; if (rg >= N) rg = N-1;
      float4 f = *(const float4*)(feat + rg*256 + c4*4);
      ushort4 u; u.x = f2bf(f.x); u.y = f2bf(f.y); u.z = f2bf(f.z); u.w = f2bf(f.w);
      uA[i] = u;
    }
  }

  for (int kt=0; kt<4; kt++){
    // ---- stage A from prefetched regs (swizzled ds_write) ----
    #pragma unroll
    for (int i=0;i<4;i++){
      int q   = i*256 + tid;
      int row = q >> 4;
      int c4  = q & 15;
      int q8 = c4 >> 1, half = c4 & 1;
      int phys = q8 ^ (row & 7);
      *(ushort4*)(sA + row*64 + phys*8 + half*4) = uA[i];
    }
    // ---- stage B: pure linear async copy of the pre-swizzled 32 KB image ----
    {
      const unsigned int* gim = (const unsigned int*)(W1aT + kt*16384);
      unsigned int* lim = (unsigned int*)sB;
      #pragma unroll
      for (int i=0;i<8;i++)
        gload_lds16(gim + i*1024 + tid*4, lim + i*1024 + tid*4);
    }
    __syncthreads();   // drains vmcnt: B tile (and ntab at kt=0) resident

    // ---- prefetch next A during the MFMA phase ----
    if (kt < 3){
      #pragma unroll
      for (int i=0;i<4;i++){
        int q   = i*256 + tid;
        int row = q >> 4;
        int c4  = q & 15;
        long rg = m0 + row; if (rg >= N) rg = N-1;
        float4 f = *(const float4*)(feat + rg*256 + (kt+1)*64 + c4*4);
        ushort4 u; u.x = f2bf(f.x); u.y = f2bf(f.y); u.z = f2bf(f.z); u.w = f2bf(f.w);
        uA[i] = u;
      }
    }

    #pragma unroll
    for (int ks=0; ks<2; ks++){
      short8_t av[4], bv[4];
      int qlog = ks*4 + qd;
      #pragma unroll
      for (int mt=0; mt<4; mt++){
        int row  = mt*16 + lr;
        int phys = qlog ^ (row & 7);
        av[mt] = *(const short8_t*)(sA + row*64 + phys*8);
      }
      #pragma unroll
      for (int nt=0; nt<4; nt++){
        int n    = wv*64 + nt*16 + lr;
        int phys = qlog ^ (n & 7);
        bv[nt] = *(const short8_t*)(sB + n*64 + phys*8);
      }
      #pragma unroll
      for (int mt=0; mt<4; mt++)
        #pragma unroll
        for (int nt=0; nt<4; nt++)
          acc[mt][nt] = __builtin_amdgcn_mfma_f32_16x16x32_bf16(av[mt], bv[nt], acc[mt][nt], 0,0,0);
    }
    __syncthreads();
  }

  // ---- epilogue: acc + b1 -> sH (rows stride 256, 16B chunks XOR-swizzled) ----
  #pragma unroll
  for (int nt=0; nt<4; nt++){
    int n = wv*64 + nt*16 + lr;
    float bias = b1[n];
    int c = n >> 3, e = n & 7;
    #pragma unroll
    for (int mt=0; mt<4; mt++)
      #pragma unroll
      for (int rr=0; rr<4; rr++){
        int m = mt*16 + qd*4 + rr;   // C/D: row = quad*4+reg, col = lane&15
        sH[m*256 + ((c ^ (m & 7))<<3) + e] = f2bf(acc[mt][nt][rr] + bias);
      }
  }
  __syncthreads();

  // ---- phase 2 (batch-merged, t from LDS) ----
  const int r = lane;
  long vg = m0 + r;
  bool rowok = vg < N; if (!rowok) vg = N-1;
  float px = vp[vg], py = vp[(size_t)N+vg], pz = vp[2*(size_t)N+vg];
  const float* tb = tlds + (size_t)wv*64*8;   // this wave's slice, in LDS
  const int rsw = r & 7;
  const unsigned short* hrow = sH + r*256;
  float opac = 1.f/(1.f+expf(-opy[vg]));  // clip(sigmoid,0,1) is a no-op

  // hoist this thread's 64 h-values (8 x ds_read_b128)
  short8_t hv[8];
  #pragma unroll
  for (int j8=0;j8<8;j8++){
    int c = wv*8 + j8;
    hv[j8] = *(const short8_t*)(hrow + ((c ^ rsw)<<3));
  }

  for (int b0=0; b0<B; b0+=2){
    int nb = (B - b0 < 2) ? (B - b0) : 2;
    float vdx0=0.f, vdy0=0.f, vdz0=0.f, sup0=-1e6f, svp0=-1e6f, szz0=-1e6f;
    float vdx1=0.f, vdy1=0.f, vdz1=0.f, sup1=-1e6f, svp1=-1e6f, szz1=-1e6f;
    #pragma unroll
    for (int bi=0; bi<2; bi++){
      if (bi < nb){
        int b = b0 + bi;
        const float* P  = pose + b*16;
        const float* Kc = intr + b*9;
        const float* Pi = poseinv + b*16;
        // per-op rounded, in numpy order, contraction OFF
        float xt = dot4_x(P[0],px, P[1],py, P[2], pz, P[3], 1.f);
        float yt = dot4_x(P[4],px, P[5],py, P[6], pz, P[7], 1.f);
        float zt = dot4_x(P[8],px, P[9],py, P[10],pz, P[11],1.f);
        float uu = dot3_x(Kc[0],xt, Kc[1],yt, Kc[2],zt);
        float vv = dot3_x(Kc[3],xt, Kc[4],yt, Kc[5],zt);
        float zp = dot3_x(Kc[6],xt, Kc[7],yt, Kc[8],zt);
        bool em = fabsf(zp) < 0.01f;
        float zsafe = em ? 0.01f : zp;
        float up   = em ? -1e6f : uu/zsafe;   // IEEE correctly-rounded divide
        float vpix = em ? -1e6f : vv/zsafe;
        float zz   = em ? -1e6f : zsafe;
        float inrm = 1.f/sqrtf(xt*xt + yt*yt + zt*zt);
        float nx=xt*inrm, ny=yt*inrm, nz=zt*inrm;
        float vx = Pi[0]*nx + Pi[1]*ny + Pi[2]*nz;
        float vy = Pi[4]*nx + Pi[5]*ny + Pi[6]*nz;
        float vz = Pi[8]*nx + Pi[9]*ny + Pi[10]*nz;
        if (bi == 0){ vdx0=vx; vdy0=vy; vdz0=vz; sup0=up; svp0=vpix; szz0=zz; }
        else        { vdx1=vx; vdy1=vy; vdz1=vz; sup1=up; svp1=vpix; szz1=zz; }
      }
    }
    // merged j-loop: t via ds_read (pipelined), h unpacked once, both batches
    float a00=0.f,a01=0.f,a02=0.f, a10=0.f,a11=0.f,a12=0.f;
    #pragma unroll
    for (int j8=0;j8<8;j8++){
      #pragma unroll
      for (int e=0;e<8;e++){
        const float* t = tb + ((j8*8+e)<<3);
        float4 tA = *(const float4*)(t);        // ds_read_b128: t0..t3
        float2 tB = *(const float2*)(t + 4);    // ds_read_b64 : t4,t5
        float hb = bf2f((unsigned short)hv[j8][e]);
        float h0 = fmaxf(hb + vdx0*tA.x + vdy0*tA.y + vdz0*tA.z, 0.f);
        float h1 = fmaxf(hb + vdx1*tA.x + vdy1*tA.y + vdz1*tA.z, 0.f);
        a00 += h0*tA.w; a01 += h0*tB.x; a02 += h0*tB.y;
        a10 += h1*tA.w; a11 += h1*tB.x; a12 += h1*tB.y;
      }
    }
    {
      int base = (wv*64 + r)*3;
      part[base+0] = a00; part[base+1] = a01; part[base+2] = a02;
      part[768+base+0] = a10; part[768+base+1] = a11; part[768+base+2] = a12;
    }
    __syncthreads();
    // all 4 waves scatter: wave w -> batch b0+(w&1); w<2: {den,num0}, w>=2: {num1,num2}
    if ((wv & 1) < nb){
      int b = b0 + (wv & 1);
      const float* pp = part + (wv & 1)*768;
      float S_up = (wv & 1) ? sup1 : sup0;
      float S_vp = (wv & 1) ? svp1 : svp0;
      float S_zz = (wv & 1) ? szz1 : szz0;
      int ix = (int)rintf(S_up);                 // round-half-even == np.round
      int iy = (int)rintf(S_vp);
      bool valid = rowok && ix>=0 && ix<WW && iy>=0 && iy<HH && S_zz>=1.0f;
      if (valid){
        int idx = iy*WW + ix;
        if (wv < 2){
          float s0 = pp[r*3+0] + pp[(64+r)*3+0] + pp[(128+r)*3+0] + pp[(192+r)*3+0];
          float r0 = 1.f/(1.f+expf(-(s0 + b2[0])));
          atomAddF32(den + (size_t)b*HWPIX + idx, opac);
          atomAddF32(num + ((size_t)b*3+0)*HWPIX + idx, opac*r0);
        } else {
          float s1 = pp[r*3+1] + pp[(64+r)*3+1] + pp[(128+r)*3+1] + pp[(192+r)*3+1];
          float s2 = pp[r*3+2] + pp[(64+r)*3+2] + pp[(128+r)*3+2] + pp[(192+r)*3+2];
          float r1 = 1.f/(1.f+expf(-(s1 + b2[1])));
          float r2 = 1.f/(1.f+expf(-(s2 + b2[2])));
          atomAddF32(num + ((size_t)b*3+1)*HWPIX + idx, opac*r1);
          atomAddF32(num + ((size_t)b*3+2)*HWPIX + idx, opac*r2);
        }
      }
    }
    if (b0 + 2 < B) __syncthreads();
  }
}

// ---------------------------------------------------------------------------
// num/den (workspace) -> final planar image; writes every out pixel, so no
// out memset is needed.
__global__ void compose_kernel(float* __restrict__ out, const float* __restrict__ num,
                               const float* __restrict__ den,
                               const float* __restrict__ bkg, int B){
  int i = blockIdx.x*256 + threadIdx.x;
  int total = B*HWPIX;
  if (i >= total) return;
  int b = i / HWPIX;
  int pix = i - b*HWPIX;
  float d = den[i];
  float alpha = 1.f - expf(-d);
  float om = 1.f - alpha;
  float dd = d + 1e-8f;
  const float* nb_ = num + (size_t)b*3*HWPIX;
  float* ob = out + (size_t)b*3*HWPIX;
  ob[0*HWPIX + pix] = (nb_[0*HWPIX + pix]/dd)*alpha + bkg[0]*om;
  ob[1*HWPIX + pix] = (nb_[1*HWPIX + pix]/dd)*alpha + bkg[1]*om;
  ob[2*HWPIX + pix] = (nb_[2*HWPIX + pix]/dd)*alpha + bkg[2]*om;
}

// ---------------------------------------------------------------------------
extern "C" void kernel_launch(void* const* d_in, const int* in_sizes, int n_in,
                              void* d_out, int out_size, void* d_ws, size_t ws_size,
                              hipStream_t stream){
  const float* vp   = (const float*)d_in[0];
  // d_in[1] = ref_images: unused by the reference computation
  const float* pose = (const float*)d_in[2];
  const float* intr = (const float*)d_in[3];
  const float* feat = (const float*)d_in[4];
  const float* opy  = (const float*)d_in[5];
  const float* W1   = (const float*)d_in[6];
  const float* b1   = (const float*)d_in[7];
  const float* W2   = (const float*)d_in[8];
  const float* b2   = (const float*)d_in[9];
  const float* bkg  = (const float*)d_in[10];
  float* out = (float*)d_out;
  int N = in_sizes[0]/3;
  int B = in_sizes[2]/16;

  char* ws = (char*)d_ws;
  float* poseinv        = (float*)ws;                          // 256 B
  unsigned short* W1aT  = (unsigned short*)(ws + 256);         // 131072 B (4 pre-swizzled kt-images)
  float* ntab           = (float*)(ws + 256 + 131072);         // 8192 B
  float* num            = (float*)(ws + 256 + 131072 + 8192);  // B*3*HWPIX floats
  float* den            = num + (size_t)B*3*HWPIX;             // B*HWPIX floats

  // prep zeroes num+den (contiguous, B*HWPIX float4s) — no memset dispatch;
  // out needs no zeroing (compose writes every pixel).
  prep_kernel<<<257, 256, 0, stream>>>(W1, W2, pose, poseinv, W1aT, ntab,
                                       num, B*HWPIX, B);
  int gridM = (N + 63)/64;
  mlp_scatter_kernel<<<gridM, 256, 0, stream>>>(feat, W1aT, b1, b2, ntab, vp, opy,
                                                pose, intr, poseinv, num, den, N, B);
  compose_kernel<<<(B*HWPIX + 255)/256, 256, 0, stream>>>(out, num, den, bkg, B);
}